// Round 1
// baseline (111.025 us; speedup 1.0000x reference)
//
#include <hip/hip_runtime.h>

#define BN_EPS 1e-5f

// ---------------------------------------------------------------------------
// Kernel 1: global average pool over H*W=4096 for each (b, c) plane.
// One 256-thread block per plane; each thread loads 4 float4 (16 floats).
// ---------------------------------------------------------------------------
__global__ __launch_bounds__(256) void pool_kernel(const float* __restrict__ x,
                                                   float* __restrict__ pooled) {
    const int plane = blockIdx.x;  // b*2048 + c, 0..32767
    const float4* xp = reinterpret_cast<const float4*>(x + (size_t)plane * 4096);
    float s = 0.f;
#pragma unroll
    for (int j = 0; j < 4; ++j) {
        float4 v = xp[threadIdx.x + j * 256];
        s += (v.x + v.y) + (v.z + v.w);
    }
    // wave (64-lane) shuffle reduction
#pragma unroll
    for (int off = 32; off > 0; off >>= 1) s += __shfl_down(s, off, 64);
    __shared__ float wsum[4];
    const int wid = threadIdx.x >> 6;
    const int lane = threadIdx.x & 63;
    if (lane == 0) wsum[wid] = s;
    __syncthreads();
    if (threadIdx.x == 0) {
        float t = (wsum[0] + wsum[1]) + (wsum[2] + wsum[3]);
        pooled[plane] = t * (1.0f / 4096.0f);
    }
}

// ---------------------------------------------------------------------------
// Kernel 2: y[b,o] = dot(pooled[b,:], W[o,:]) ; BN(eval) ; ReLU ; broadcast
// each y[b,o] to the 4096-float output plane. One wave per (b,o).
// 4096 waves total -> 1024 blocks x 256 threads (4 waves/block).
// ---------------------------------------------------------------------------
__global__ __launch_bounds__(256) void gemm_bn_bcast_kernel(
    const float* __restrict__ pooled, const float* __restrict__ Wm,
    const float* __restrict__ gamma, const float* __restrict__ beta,
    const float* __restrict__ rmean, const float* __restrict__ rvar,
    float* __restrict__ out) {
    const int wid = threadIdx.x >> 6;
    const int lane = threadIdx.x & 63;
    const int gw = blockIdx.x * 4 + wid;  // 0..4095
    const int b = gw >> 8;                 // 0..15
    const int o = gw & 255;                // 0..255

    const float4* pr = reinterpret_cast<const float4*>(pooled + b * 2048);
    const float4* wr = reinterpret_cast<const float4*>(Wm + (size_t)o * 2048);
    float s = 0.f;
#pragma unroll
    for (int k = 0; k < 8; ++k) {
        float4 p = pr[lane + k * 64];
        float4 w = wr[lane + k * 64];
        s += p.x * w.x + p.y * w.y + p.z * w.z + p.w * w.w;
    }
#pragma unroll
    for (int off = 32; off > 0; off >>= 1) s += __shfl_down(s, off, 64);
    float y = __shfl(s, 0, 64);

    const float inv_std = rsqrtf(rvar[o] + BN_EPS);
    y = (y - rmean[o]) * (gamma[o] * inv_std) + beta[o];
    y = fmaxf(y, 0.f);

    float4 v = make_float4(y, y, y, y);
    float4* op = reinterpret_cast<float4*>(out + (size_t)gw * 4096);
#pragma unroll
    for (int j = 0; j < 16; ++j) op[j * 64 + lane] = v;
}

extern "C" void kernel_launch(void* const* d_in, const int* in_sizes, int n_in,
                              void* d_out, int out_size, void* d_ws, size_t ws_size,
                              hipStream_t stream) {
    const float* x     = (const float*)d_in[0];  // [16, 2048, 64, 64]
    const float* Wm    = (const float*)d_in[1];  // [256, 2048]
    const float* gamma = (const float*)d_in[2];  // [256]
    const float* beta  = (const float*)d_in[3];  // [256]
    const float* rmean = (const float*)d_in[4];  // [256]
    const float* rvar  = (const float*)d_in[5];  // [256]
    float* out = (float*)d_out;                  // [16, 256, 64, 64]

    float* pooled = (float*)d_ws;                // [16, 2048] = 128 KiB

    pool_kernel<<<16 * 2048, 256, 0, stream>>>(x, pooled);
    gemm_bn_bcast_kernel<<<4096 / 4, 256, 0, stream>>>(pooled, Wm, gamma, beta,
                                                       rmean, rvar, out);
}